// Round 11
// baseline (191.295 us; speedup 1.0000x reference)
//
#include <hip/hip_runtime.h>
#include <hip/hip_bf16.h>
#include <stdint.h>

#define M_TOT 16384
#define N_TOT 2048
#define K_TOT 2048
#define NT 32            // K-tiles of BK=64

typedef __attribute__((ext_vector_type(8))) short bf16x8;
typedef __attribute__((ext_vector_type(4))) float f32x4;

__device__ __forceinline__ ushort f32_to_bf16_rne(float f) {
    uint32_t u = __float_as_uint(f);
    uint32_t r = (u + 0x7fffu + ((u >> 16) & 1u)) >> 16;
    return (ushort)r;
}

__device__ __forceinline__ void async_copy16(const void* gptr, void* lptr) {
    __builtin_amdgcn_global_load_lds(
        (const __attribute__((address_space(1))) uint32_t*)gptr,
        (__attribute__((address_space(3))) uint32_t*)lptr,
        16, 0, 0);
}

// ---------------------------------------------------------------------------
// Fake-quantize x: per (row, 32-col) block, symmetric int8 -> bf16.
// ---------------------------------------------------------------------------
__global__ void quant_x_kernel(const float* __restrict__ x, ushort* __restrict__ qx) {
    const int tid = blockIdx.x * 256 + threadIdx.x;
    const float4 v = ((const float4*)x)[tid];
    float m = fmaxf(fmaxf(fabsf(v.x), fabsf(v.y)), fmaxf(fabsf(v.z), fabsf(v.w)));
    m = fmaxf(m, __shfl_xor(m, 1));
    m = fmaxf(m, __shfl_xor(m, 2));
    m = fmaxf(m, __shfl_xor(m, 4));
    const float s = (m > 0.f) ? (m / 127.f) : 1.f;
    const float q0 = fminf(fmaxf(rintf(v.x / s), -127.f), 127.f) * s;
    const float q1 = fminf(fmaxf(rintf(v.y / s), -127.f), 127.f) * s;
    const float q2 = fminf(fmaxf(rintf(v.z / s), -127.f), 127.f) * s;
    const float q3 = fminf(fmaxf(rintf(v.w / s), -127.f), 127.f) * s;
    ushort4 r;
    r.x = f32_to_bf16_rne(q0);
    r.y = f32_to_bf16_rne(q1);
    r.z = f32_to_bf16_rne(q2);
    r.w = f32_to_bf16_rne(q3);
    ((ushort4*)qx)[tid] = r;
}

// ---------------------------------------------------------------------------
// Fake-quantize weight (kept [Dout][Din] == B^T layout). 32x32 blocks.
// ---------------------------------------------------------------------------
__global__ void quant_w_kernel(const float* __restrict__ w, ushort* __restrict__ qw) {
    const int gtid = blockIdx.x * 256 + threadIdx.x;
    const int wid  = gtid >> 6;
    const int lane = gtid & 63;
    const int tn = wid >> 6;
    const int tk = wid & 63;
    const int row = tn * 32 + (lane >> 1);
    const int col = tk * 32 + ((lane & 1) << 4);
    const float* p = w + (size_t)row * K_TOT + col;
    const float4 v0 = ((const float4*)p)[0];
    const float4 v1 = ((const float4*)p)[1];
    const float4 v2 = ((const float4*)p)[2];
    const float4 v3 = ((const float4*)p)[3];
    float m = 0.f;
#define MAX4(V) m = fmaxf(m, fmaxf(fmaxf(fabsf(V.x), fabsf(V.y)), fmaxf(fabsf(V.z), fabsf(V.w))));
    MAX4(v0) MAX4(v1) MAX4(v2) MAX4(v3)
#undef MAX4
    #pragma unroll
    for (int off = 1; off < 64; off <<= 1) m = fmaxf(m, __shfl_xor(m, off));
    const float s = (m > 0.f) ? (m / 127.f) : 1.f;
    float vv[16] = {v0.x, v0.y, v0.z, v0.w, v1.x, v1.y, v1.z, v1.w,
                    v2.x, v2.y, v2.z, v2.w, v3.x, v3.y, v3.z, v3.w};
    union { ushort us[16]; uint4 q[2]; } o;
    #pragma unroll
    for (int i = 0; i < 16; ++i) {
        const float q = fminf(fmaxf(rintf(vv[i] / s), -127.f), 127.f) * s;
        o.us[i] = f32_to_bf16_rne(q);
    }
    uint4* dst = (uint4*)(qw + (size_t)row * K_TOT + col);
    dst[0] = o.q[0];
    dst[1] = o.q[1];
}

// ---------------------------------------------------------------------------
// 128x128 bf16 GEMM, 4 waves (2x2), BK=64, 2 BLOCKS/CU (80 KB LDS each:
// A double-buf 32 KB + B 3-slot 48 KB).  Cross-block TLP hides each block's
// sync slack; square per-wave tile (64x64) cuts LDS read redundancy to 2x/2x
// (128 b128/CU-tile-pair vs 192 at 256²  ->  LDS floor 60 -> 40 µs/CU).
// Per tile (R9-proven wait structure): phases p0..p3, one mg (16 rows) each;
// per phase {2 af reads (+8 bg at p0), 2 stage calls, lgkm(2,2,2,0), 8 MFMA}.
// Staging: A(t+1) at p0-p1 (dbuf), B(t+2) at p2-p3 (slot (t+2)%3).
// vmcnt(4) at p3 drains A(t+1), keeps B(t+2) in flight.  ONE barrier/tile.
// ---------------------------------------------------------------------------
#define LDSA(tb, row, colus) \
    (*(const bf16x8*)&As[tb][row][(colus) ^ (((row) & 7) << 3)])
#define LDSB(slot, row, colus) \
    (*(const bf16x8*)&Bs[slot][row][(colus) ^ (((row) & 7) << 3)])

// one call covers 32 rows (256 thr x 16 B); q4 = row-quarter 0..3
#define STAGE_A(tb, q4, tt)                                                              \
    async_copy16(Agbase + (size_t)((q4) * 32) * K_TOT + (size_t)(tt) * 64,               \
                 (char*)&As[0][0][0] + (tb) * 16384 + (q4) * 4096 + (wv << 10));
#define STAGE_B(slot, q4, tt)                                                            \
    async_copy16(Bgbase + (size_t)((q4) * 32) * K_TOT + (size_t)(tt) * 64,               \
                 (char*)&Bs[0][0][0] + (size_t)(slot) * 16384 + (q4) * 4096 + (wv << 10));

#define WAITLG(N) { asm volatile("s_waitcnt lgkmcnt(" #N ")" ::: "memory"); __builtin_amdgcn_sched_barrier(0); }

// 2 A-fragments of m-group mg (rows base+mg*16, k lo/hi halves)
#define RD_AFG(DST, tb, mg) {                                 \
    DST[0] = LDSA(tb, ab + (mg) * 16,      h8);               \
    DST[1] = LDSA(tb, ab + (mg) * 16, 32 + h8); }

// 8 B-fragments (4 n-groups x 2 k-halves) from slot
#define RD_BG(slot) {                                                         \
    _Pragma("unroll")                                                         \
    for (int j = 0; j < 4; ++j) {                                             \
        const int bb_ = bbs + j * 16;                                         \
        bg[j][0] = LDSB(slot, bb_, h8);  bg[j][1] = LDSB(slot, bb_, 32 + h8); \
    } }

#define MFMA_PH(mg, AF)                                                                   \
    __builtin_amdgcn_s_setprio(1);                                                        \
    _Pragma("unroll")                                                                     \
    for (int j = 0; j < 4; ++j) {                                                         \
        acc[mg][j] = __builtin_amdgcn_mfma_f32_16x16x32_bf16(AF[0], bg[j][0], acc[mg][j], 0, 0, 0); \
        acc[mg][j] = __builtin_amdgcn_mfma_f32_16x16x32_bf16(AF[1], bg[j][1], acc[mg][j], 0, 0, 0); \
    }                                                                                     \
    __builtin_amdgcn_s_setprio(0);

// One K-tile.  tb=t&1; BRD=t%3 (B read slot); BWR=(t+2)%3 (B stage slot).
// STA: stage A(t+1); STB: stage B(t+2); VMC: 4 / 0 / -1.
#define TILE_BODY(tb, t, STA, STB, VMC, BRD, BWR)                                         \
  {                                                                                       \
    /* -- p0: afX(mg0) + bg(8) + afY(mg1); stage A(t+1) q0,q1; drain afX+bg -- */         \
    RD_AFG(afX, tb, 0)                                                                    \
    RD_BG(BRD)                                                                            \
    __builtin_amdgcn_sched_barrier(0);   /* afY must be newest (drain boundary) */        \
    RD_AFG(afY, tb, 1)                                                                    \
    if (STA) { STAGE_A(tb ^ 1, 0, (t) + 1) STAGE_A(tb ^ 1, 1, (t) + 1) }                  \
    WAITLG(2)                                                                             \
    MFMA_PH(0, afX)                                                                       \
    /* -- p1: afX(mg2); stage A(t+1) q2,q3; drain afY -- */                               \
    RD_AFG(afX, tb, 2)                                                                    \
    if (STA) { STAGE_A(tb ^ 1, 2, (t) + 1) STAGE_A(tb ^ 1, 3, (t) + 1) }                  \
    WAITLG(2)                                                                             \
    MFMA_PH(1, afY)                                                                       \
    /* -- p2: afY(mg3); stage B(t+2) q0,q1 into disjoint slot; drain afX -- */            \
    RD_AFG(afY, tb, 3)                                                                    \
    if (STB) { STAGE_B(BWR, 0, (t) + 2) STAGE_B(BWR, 1, (t) + 2) }                        \
    WAITLG(2)                                                                             \
    MFMA_PH(2, afX)                                                                       \
    /* -- p3: stage B(t+2) q2,q3; drain afY; counted vmcnt; sole barrier -- */            \
    if (STB) { STAGE_B(BWR, 2, (t) + 2) STAGE_B(BWR, 3, (t) + 2) }                        \
    WAITLG(0)                                                                             \
    MFMA_PH(3, afY)                                                                       \
    if ((VMC) == 4)      { asm volatile("s_waitcnt vmcnt(4)" ::: "memory"); }             \
    else if ((VMC) == 0) { asm volatile("s_waitcnt vmcnt(0)" ::: "memory"); }             \
    __builtin_amdgcn_s_barrier();  /* staged A(t+1)/B(t+1) collectively visible */        \
  }

#define ROT { brd = (brd == 2) ? 0 : brd + 1;  bwr = (bwr == 2) ? 0 : bwr + 1; }

__global__ __launch_bounds__(256, 2) void gemm_tlp_kernel(
    const ushort* __restrict__ A,    // [M][K] bf16 bits
    const ushort* __restrict__ Bt,   // [N][K] bf16 bits
    const float* __restrict__ bias,  // [N]
    float* __restrict__ C) {         // [M][N]

    __shared__ ushort As[2][128][64];   // 32 KB
    __shared__ ushort Bs[3][128][64];   // 48 KB -> 80 KB total, 2 blocks/CU

    const int tid  = threadIdx.x;
    const int lane = tid & 63;
    const int wv   = tid >> 6;          // wave 0..3
    const int wmr  = wv >> 1;           // 0..1  (M)
    const int wcn  = wv & 1;            // 0..1  (N)
    const int r    = lane & 15;
    const int h8   = (lane >> 4) << 3;  // 0,8,16,24 (ushort col of k-frag)

    // bijective XCD swizzle (nwg = 2048, 2048 % 8 == 0)
    const int nbn  = N_TOT / 128;                 // 16
    const int nwg  = (M_TOT / 128) * nbn;         // 2048
    const int cpx  = nwg >> 3;
    const int swz  = (blockIdx.x & 7) * cpx + (blockIdx.x >> 3);
    const int brow = (swz / nbn) * 128;
    const int bcol = (swz % nbn) * 128;

    // staging: thread -> row tid>>3 (0..31 per call), 16B at pre-swizzled col
    const int srow = tid >> 3;
    const int scol = (((tid & 7) ^ (srow & 7)) << 3);
    const ushort* Agbase = A  + (size_t)(brow + srow) * K_TOT + scol;
    const ushort* Bgbase = Bt + (size_t)(bcol + srow) * K_TOT + scol;

    const int ab  = wmr * 64 + r;       // wave's A row base
    const int bbs = wcn * 64 + r;       // wave's B row base

    f32x4 acc[4][4];
    const f32x4 zero = {0.f, 0.f, 0.f, 0.f};
    #pragma unroll
    for (int i = 0; i < 4; ++i)
        #pragma unroll
        for (int j = 0; j < 4; ++j) acc[i][j] = zero;

    // ---- prologue: A(0)->As0, B(0)->slot0, B(1)->slot1 (4 calls each);
    //      vmcnt(4) drains A(0)+B(0), keeps B(1) in flight; barrier ----
    STAGE_A(0, 0, 0) STAGE_A(0, 1, 0) STAGE_A(0, 2, 0) STAGE_A(0, 3, 0)
    STAGE_B(0, 0, 0) STAGE_B(0, 1, 0) STAGE_B(0, 2, 0) STAGE_B(0, 3, 0)
    STAGE_B(1, 0, 1) STAGE_B(1, 1, 1) STAGE_B(1, 2, 1) STAGE_B(1, 3, 1)
    asm volatile("s_waitcnt vmcnt(4)" ::: "memory");
    __builtin_amdgcn_s_barrier();

    bf16x8 afX[2], afY[2];
    bf16x8 bg[4][2];

    int brd = 0;   // B read slot  = t%3
    int bwr = 2;   // B stage slot = (t+2)%3

    for (int t = 0; t < NT - 2; t += 2) {
        TILE_BODY(0, t,     1, 1, 4, brd, bwr)
        ROT
        TILE_BODY(1, t + 1, 1, 1, 4, brd, bwr)
        ROT
    }
    TILE_BODY(0, NT - 2, 1, 0, 0, brd, 0)    // stage A(31) only; drain all
    brd = (brd == 2) ? 0 : brd + 1;
    TILE_BODY(1, NT - 1, 0, 0, -1, brd, 0)   // pure compute

    // ---- epilogue: bias + store (C/D layout: col=lane&15, row=(lane>>4)*4+reg)
    const int hq = (lane >> 4) * 4;
    float bv[4];
    #pragma unroll
    for (int j = 0; j < 4; ++j) bv[j] = bias[bcol + wcn * 64 + j * 16 + r];
    #pragma unroll
    for (int i = 0; i < 4; ++i) {
        const int row0 = brow + wmr * 64 + i * 16 + hq;
        #pragma unroll
        for (int j = 0; j < 4; ++j) {
            const int col = bcol + wcn * 64 + j * 16 + r;
            #pragma unroll
            for (int jj = 0; jj < 4; ++jj)
                C[(size_t)(row0 + jj) * N_TOT + col] = acc[i][j][jj] + bv[j];
        }
    }
}

extern "C" void kernel_launch(void* const* d_in, const int* in_sizes, int n_in,
                              void* d_out, int out_size, void* d_ws, size_t ws_size,
                              hipStream_t stream) {
    const float* x    = (const float*)d_in[0];   // [4,4096,2048]
    const float* wgt  = (const float*)d_in[1];   // [2048,2048]
    const float* bias = (const float*)d_in[2];   // [2048]
    float* out = (float*)d_out;                  // [4,4096,2048]

    ushort* qx = (ushort*)d_ws;                          // 64 MB
    ushort* qw = qx + (size_t)M_TOT * K_TOT;             // 8 MB

    quant_x_kernel<<<(M_TOT * K_TOT / 4) / 256, 256, 0, stream>>>(x, qx);
    quant_w_kernel<<<(64 * 64 * 64) / 256, 256, 0, stream>>>(wgt, qw);
    gemm_tlp_kernel<<<(M_TOT / 128) * (N_TOT / 128), 256, 0, stream>>>(qx, qw, bias, out);
}

// Round 12
// 163.035 us; speedup vs baseline: 1.1733x; 1.1733x over previous
//
#include <hip/hip_runtime.h>
#include <hip/hip_bf16.h>
#include <stdint.h>

#define M_TOT 16384
#define N_TOT 2048
#define K_TOT 2048
#define NT 32            // K-tiles of BK=64
#define QW_BLOCKS 1024   // quant_w blocks (4096 tiles / 4 waves per block)

typedef __attribute__((ext_vector_type(8))) short bf16x8;
typedef __attribute__((ext_vector_type(4))) float f32x4;

__device__ __forceinline__ ushort f32_to_bf16_rne(float f) {
    uint32_t u = __float_as_uint(f);
    uint32_t r = (u + 0x7fffu + ((u >> 16) & 1u)) >> 16;
    return (ushort)r;
}

__device__ __forceinline__ void async_copy16(const void* gptr, void* lptr) {
    __builtin_amdgcn_global_load_lds(
        (const __attribute__((address_space(1))) uint32_t*)gptr,
        (__attribute__((address_space(3))) uint32_t*)lptr,
        16, 0, 0);
}

// ---------------------------------------------------------------------------
// Merged fake-quant kernel.  Blocks [0, QW_BLOCKS): weight 32x32 tiles
// (scheduled first, finish early).  Blocks [QW_BLOCKS, ...): x rows,
// per (row, 32-col) block, 8 lanes per block via shfl_xor maxabs.
// ---------------------------------------------------------------------------
__global__ void quant_fused_kernel(const float* __restrict__ x,
                                   const float* __restrict__ w,
                                   ushort* __restrict__ qx,
                                   ushort* __restrict__ qw) {
    if (blockIdx.x < QW_BLOCKS) {
        // ---- weight path ----
        const int gtid = blockIdx.x * 256 + threadIdx.x;
        const int wid  = gtid >> 6;        // tile id 0..4095
        const int lane = gtid & 63;
        const int tn = wid >> 6;
        const int tk = wid & 63;
        const int row = tn * 32 + (lane >> 1);
        const int col = tk * 32 + ((lane & 1) << 4);
        const float* p = w + (size_t)row * K_TOT + col;
        const float4 v0 = ((const float4*)p)[0];
        const float4 v1 = ((const float4*)p)[1];
        const float4 v2 = ((const float4*)p)[2];
        const float4 v3 = ((const float4*)p)[3];
        float m = 0.f;
#define MAX4(V) m = fmaxf(m, fmaxf(fmaxf(fabsf(V.x), fabsf(V.y)), fmaxf(fabsf(V.z), fabsf(V.w))));
        MAX4(v0) MAX4(v1) MAX4(v2) MAX4(v3)
#undef MAX4
        #pragma unroll
        for (int off = 1; off < 64; off <<= 1) m = fmaxf(m, __shfl_xor(m, off));
        const float s = (m > 0.f) ? (m / 127.f) : 1.f;
        float vv[16] = {v0.x, v0.y, v0.z, v0.w, v1.x, v1.y, v1.z, v1.w,
                        v2.x, v2.y, v2.z, v2.w, v3.x, v3.y, v3.z, v3.w};
        union { ushort us[16]; uint4 q[2]; } o;
        #pragma unroll
        for (int i = 0; i < 16; ++i) {
            const float q = fminf(fmaxf(rintf(vv[i] / s), -127.f), 127.f) * s;
            o.us[i] = f32_to_bf16_rne(q);
        }
        uint4* dst = (uint4*)(qw + (size_t)row * K_TOT + col);
        dst[0] = o.q[0];
        dst[1] = o.q[1];
    } else {
        // ---- x path ----
        const int tid = (blockIdx.x - QW_BLOCKS) * 256 + threadIdx.x;
        const float4 v = ((const float4*)x)[tid];
        float m = fmaxf(fmaxf(fabsf(v.x), fabsf(v.y)), fmaxf(fabsf(v.z), fabsf(v.w)));
        m = fmaxf(m, __shfl_xor(m, 1));
        m = fmaxf(m, __shfl_xor(m, 2));
        m = fmaxf(m, __shfl_xor(m, 4));
        const float s = (m > 0.f) ? (m / 127.f) : 1.f;
        const float q0 = fminf(fmaxf(rintf(v.x / s), -127.f), 127.f) * s;
        const float q1 = fminf(fmaxf(rintf(v.y / s), -127.f), 127.f) * s;
        const float q2 = fminf(fmaxf(rintf(v.z / s), -127.f), 127.f) * s;
        const float q3 = fminf(fmaxf(rintf(v.w / s), -127.f), 127.f) * s;
        ushort4 r;
        r.x = f32_to_bf16_rne(q0);
        r.y = f32_to_bf16_rne(q1);
        r.z = f32_to_bf16_rne(q2);
        r.w = f32_to_bf16_rne(q3);
        ((ushort4*)qx)[tid] = r;
    }
}

// ---------------------------------------------------------------------------
// 256x256 bf16 GEMM — R9 (best measured): R5 flattened-read schedule with the
// mid-tile barrier removed via B triple-buffering.  LDS: As[2] 64KB + Bs[3]
// 96KB = 160KB (1 block/CU).  B(t) in slot t%3; B(t+2) staged into (t+2)%3
// -> disjoint from all reads for any intra-tile wave skew -> no WAR fence.
// ONE barrier per tile (p3, after vmcnt(4)).
// lgkm trace (per wave): p0 wait drains bg8+afX4 (leaves afY); p1 drains afY
// (leaves afX); p2 drains afX (leaves afY); p3 lgkm(0).
// vmcnt steady state at p3: 12 in flight -> vmcnt(4) drains B(t+1)+A(t+1),
// keeps B(t+2) in flight.
// ---------------------------------------------------------------------------
#define LDSA(tb, row, colus) \
    (*(const bf16x8*)&As[tb][row][(colus) ^ (((row) & 7) << 3)])
#define LDSB(slot, row, colus) \
    (*(const bf16x8*)&Bs[slot][row][(colus) ^ (((row) & 7) << 3)])

#define STAGE_A(tb, hh, li, tt)                                                          \
    async_copy16(Agbase + (size_t)((hh) * 128 + (li) * 64) * K_TOT + (size_t)(tt) * 64,  \
                 (char*)&As[0][0][0] + (tb) * 32768 + (hh) * 16384 + (li) * 8192 + (wv << 10));
#define STAGE_B(slot, hh, li, tt)                                                        \
    async_copy16(Bgbase + (size_t)((hh) * 128 + (li) * 64) * K_TOT + (size_t)(tt) * 64,  \
                 (char*)&Bs[0][0][0] + (size_t)(slot) * 32768 + (hh) * 16384 + (li) * 8192 + (wv << 10));
#define STAGE_A2(tb, hh, tt)    { STAGE_A(tb, hh, 0, tt) STAGE_A(tb, hh, 1, tt) }
#define STAGE_B2(slot, hh, tt)  { STAGE_B(slot, hh, 0, tt) STAGE_B(slot, hh, 1, tt) }

#define WAITLGKM4 { asm volatile("s_waitcnt lgkmcnt(4)" ::: "memory"); __builtin_amdgcn_sched_barrier(0); }
#define WAITLGKM0 { asm volatile("s_waitcnt lgkmcnt(0)" ::: "memory"); __builtin_amdgcn_sched_barrier(0); }

// read the 4 A-fragments of row-pair q (rows q*32, q*32+16; k lo/hi halves)
#define RD_AF(DST, tb, q) {                                   \
    DST[0] = LDSA(tb, ab + (q) * 32,      h8);                \
    DST[1] = LDSA(tb, ab + (q) * 32,      32 + h8);           \
    DST[2] = LDSA(tb, ab + (q) * 32 + 16, h8);                \
    DST[3] = LDSA(tb, ab + (q) * 32 + 16, 32 + h8); }

#define RD_BG(slot) {                                                         \
    _Pragma("unroll")                                                         \
    for (int j = 0; j < 4; ++j) {                                             \
        const int bb = wcn * 64 + j * 16 + r;                                 \
        bg[j][0] = LDSB(slot, bb, h8);  bg[j][1] = LDSB(slot, bb, 32 + h8);   \
    } }

#define MFMA_PH(i0, AF)                                                                   \
    __builtin_amdgcn_s_setprio(1);                                                        \
    _Pragma("unroll")                                                                     \
    for (int j = 0; j < 4; ++j) {                                                         \
        acc[i0][j]     = __builtin_amdgcn_mfma_f32_16x16x32_bf16(AF[0], bg[j][0], acc[i0][j], 0, 0, 0);     \
        acc[i0][j]     = __builtin_amdgcn_mfma_f32_16x16x32_bf16(AF[1], bg[j][1], acc[i0][j], 0, 0, 0);     \
        acc[(i0)+1][j] = __builtin_amdgcn_mfma_f32_16x16x32_bf16(AF[2], bg[j][0], acc[(i0)+1][j], 0, 0, 0); \
        acc[(i0)+1][j] = __builtin_amdgcn_mfma_f32_16x16x32_bf16(AF[3], bg[j][1], acc[(i0)+1][j], 0, 0, 0); \
    }                                                                                     \
    __builtin_amdgcn_s_setprio(0);

// One K-tile.  tb = t&1 (A buffer).  BRD: B read slot (t%3); BWR: B stage
// slot ((t+2)%3).  STA/STB gate staging; VMC: 4 / 0 / -1 (skip).
#define TILE_BODY(tb, t, STA, STB, VMC, BRD, BWR)                                         \
  {                                                                                       \
    /* -- p0: afX(q0) + bg(8) + afY(q1); stage A(t+1)h0; drain afX+bg -- */               \
    RD_AF(afX, tb, 0)                                                                     \
    RD_BG(BRD)                                                                            \
    RD_AF(afY, tb, 1)                                                                     \
    if (STA) STAGE_A2(tb ^ 1, 0, (t) + 1)                                                 \
    WAITLGKM4                                                                             \
    MFMA_PH(0, afX)                                                                       \
    /* -- p1: afX(q2); stage A(t+1)h1; drain afY -- */                                    \
    RD_AF(afX, tb, 2)                                                                     \
    if (STA) STAGE_A2(tb ^ 1, 1, (t) + 1)                                                 \
    WAITLGKM4                                                                             \
    MFMA_PH(2, afY)                                                                       \
    /* -- p2: afY(q3); stage B(t+2)h0 into disjoint slot; drain afX -- */                 \
    RD_AF(afY, tb, 3)                                                                     \
    if (STB) STAGE_B2(BWR, 0, (t) + 2)                                                    \
    WAITLGKM4                                                                             \
    MFMA_PH(4, afX)                                                                       \
    /* -- p3: stage B(t+2)h1; drain afY; counted vmcnt; sole barrier -- */                \
    if (STB) STAGE_B2(BWR, 1, (t) + 2)                                                    \
    WAITLGKM0                                                                             \
    MFMA_PH(6, afY)                                                                       \
    if ((VMC) == 4)      { asm volatile("s_waitcnt vmcnt(4)" ::: "memory"); }             \
    else if ((VMC) == 0) { asm volatile("s_waitcnt vmcnt(0)" ::: "memory"); }             \
    __builtin_amdgcn_s_barrier();  /* staged A(t+1)/B(t+1) collectively visible */        \
  }

__global__ __launch_bounds__(512, 2) void gemm_pipe5_kernel(
    const ushort* __restrict__ A,    // [M][K] bf16 bits
    const ushort* __restrict__ Bt,   // [N][K] bf16 bits
    const float* __restrict__ bias,  // [N]
    float* __restrict__ C) {         // [M][N]

    __shared__ ushort As[2][256][64];   // 64 KB
    __shared__ ushort Bs[3][256][64];   // 96 KB (triple-buffered B)

    const int tid  = threadIdx.x;
    const int lane = tid & 63;
    const int wv   = tid >> 6;          // wave 0..7
    const int wmr  = wv >> 2;           // 0..1  (M)
    const int wcn  = wv & 3;            // 0..3  (N)
    const int r    = lane & 15;
    const int h8   = (lane >> 4) << 3;  // 0,8,16,24 (ushort col of k-frag)

    // bijective XCD swizzle (nwg = 512)
    const int nbn  = N_TOT / 256;                 // 8
    const int nwg  = (M_TOT / 256) * nbn;         // 512
    const int cpx  = nwg >> 3;
    const int swz  = (blockIdx.x & 7) * cpx + (blockIdx.x >> 3);
    const int brow = (swz / nbn) * 256;
    const int bcol = (swz % nbn) * 256;

    // staging: thread -> row tid>>3 of each 64-row group, 16B at pre-swizzled col
    const int srow = tid >> 3;
    const int scol = (((tid & 7) ^ (srow & 7)) << 3);
    const ushort* Agbase = A  + (size_t)(brow + srow) * K_TOT + scol;
    const ushort* Bgbase = Bt + (size_t)(bcol + srow) * K_TOT + scol;

    const int ab = wmr * 128 + r;       // wave's A row base

    f32x4 acc[8][4];
    const f32x4 zero = {0.f, 0.f, 0.f, 0.f};
    #pragma unroll
    for (int i = 0; i < 8; ++i)
        #pragma unroll
        for (int j = 0; j < 4; ++j) acc[i][j] = zero;

    // ---- prologue: A(0)->As0, B(0)->slot0, B(1)->slot1; vmcnt(4) keeps B(1)
    //      in flight; barrier ----
    STAGE_A2(0, 0, 0) STAGE_A2(0, 1, 0)
    STAGE_B2(0, 0, 0) STAGE_B2(0, 1, 0)
    STAGE_B2(1, 0, 1) STAGE_B2(1, 1, 1)
    asm volatile("s_waitcnt vmcnt(4)" ::: "memory");
    __builtin_amdgcn_s_barrier();

    bf16x8 afX[4], afY[4];
    bf16x8 bg[4][2];

    int brd = 0;   // B read slot  = t%3
    int bwr = 2;   // B stage slot = (t+2)%3

    for (int t = 0; t < NT - 2; t += 2) {
        TILE_BODY(0, t,     1, 1, 4, brd, bwr)
        brd = (brd == 2) ? 0 : brd + 1;  bwr = (bwr == 2) ? 0 : bwr + 1;
        TILE_BODY(1, t + 1, 1, 1, 4, brd, bwr)
        brd = (brd == 2) ? 0 : brd + 1;  bwr = (bwr == 2) ? 0 : bwr + 1;
    }
    TILE_BODY(0, NT - 2, 1, 0, 0, brd, 0)    // stage A(31) only; drain all
    brd = (brd == 2) ? 0 : brd + 1;
    TILE_BODY(1, NT - 1, 0, 0, -1, brd, 0)   // pure compute

    // ---- epilogue: bias + store (C/D layout: col=lane&15, row=(lane>>4)*4+reg)
    const int hq = (lane >> 4) * 4;
    float bv[4];
    #pragma unroll
    for (int j = 0; j < 4; ++j) bv[j] = bias[bcol + wcn * 64 + j * 16 + r];
    #pragma unroll
    for (int i = 0; i < 8; ++i) {
        const int row0 = brow + wmr * 128 + i * 16 + hq;
        #pragma unroll
        for (int j = 0; j < 4; ++j) {
            const int col = bcol + wcn * 64 + j * 16 + r;
            #pragma unroll
            for (int jj = 0; jj < 4; ++jj)
                C[(size_t)(row0 + jj) * N_TOT + col] = acc[i][j][jj] + bv[j];
        }
    }
}

extern "C" void kernel_launch(void* const* d_in, const int* in_sizes, int n_in,
                              void* d_out, int out_size, void* d_ws, size_t ws_size,
                              hipStream_t stream) {
    const float* x    = (const float*)d_in[0];   // [4,4096,2048]
    const float* wgt  = (const float*)d_in[1];   // [2048,2048]
    const float* bias = (const float*)d_in[2];   // [2048]
    float* out = (float*)d_out;                  // [4,4096,2048]

    ushort* qx = (ushort*)d_ws;                          // 64 MB
    ushort* qw = qx + (size_t)M_TOT * K_TOT;             // 8 MB

    quant_fused_kernel<<<QW_BLOCKS + (M_TOT * K_TOT / 4) / 256, 256, 0, stream>>>(x, wgt, qx, qw);
    gemm_pipe5_kernel<<<(M_TOT / 256) * (N_TOT / 256), 512, 0, stream>>>(qx, qw, bias, out);
}